// Round 12
// baseline (6264.828 us; speedup 1.0000x reference)
//
#include <hip/hip_runtime.h>
#include <math.h>

#define NWG 256
#define NTH 512

typedef float vf2 __attribute__((ext_vector_type(2)));

// agent-coherent (L2-bypassing) access — cross-XCD exchange primitives
__device__ __forceinline__ float cload(const float* p) {
    return __hip_atomic_load(p, __ATOMIC_RELAXED, __HIP_MEMORY_SCOPE_AGENT);
}
__device__ __forceinline__ void cstore(float* p, float v) {
    __hip_atomic_store(p, v, __ATOMIC_RELAXED, __HIP_MEMORY_SCOPE_AGENT);
}
__device__ __forceinline__ vf2 cload2(const float* p) {
    unsigned long long u = __hip_atomic_load((const unsigned long long*)p,
                                             __ATOMIC_RELAXED, __HIP_MEMORY_SCOPE_AGENT);
    vf2 r;
    r.x = __uint_as_float((unsigned)u);
    r.y = __uint_as_float((unsigned)(u >> 32));
    return r;
}

// two-level arrive (16 groups x 16 WGs); gen monotonic, counters never reset
__device__ __forceinline__ void bar_arrive(unsigned* tree, int w, unsigned gen) {
    unsigned p = __hip_atomic_fetch_add(&tree[(w >> 4) * 16], 1u,
                                        __ATOMIC_RELAXED, __HIP_MEMORY_SCOPE_AGENT);
    if (p + 1u == 16u * gen) {
        unsigned q = __hip_atomic_fetch_add(&tree[272], 1u,
                                            __ATOMIC_RELAXED, __HIP_MEMORY_SCOPE_AGENT);
        if (q + 1u == 16u * gen)
            __hip_atomic_store(&tree[288], gen,
                               __ATOMIC_RELAXED, __HIP_MEMORY_SCOPE_AGENT);
    }
}
__device__ __forceinline__ void bar_wait(unsigned* tree, unsigned gen) {
    unsigned f;
    do {
        f = __hip_atomic_load(&tree[288], __ATOMIC_RELAXED, __HIP_MEMORY_SCOPE_AGENT);
        if (f < gen) __builtin_amdgcn_s_sleep(2);
    } while (f < gen);
}

// init: initial h states -> pair-layout parity-1 buffers; zero barriers
__global__ void k_init(const float* __restrict__ h0in, float* __restrict__ h0buf,
                       float* __restrict__ h1buf, unsigned* __restrict__ bar) {
    int i = blockIdx.x * 256 + threadIdx.x;
    if (i < 32768) {
        int m = i >> 9, k = i & 511;
        h0buf[32768 + ((k >> 1) << 7) + (m << 1) + (k & 1)] = h0in[i];
    } else if (i < 65536) {
        int j = i - 32768;
        int m = j >> 9, k = j & 511;
        h1buf[32768 + ((k >> 1) << 7) + (m << 1) + (k & 1)] = h0in[i];
    } else if (i < 66560) {
        bar[i - 65536] = 0u;
    }
}

// transpose x [64][512][16] -> xT [512][64][16]
__global__ void k_xt(const float* __restrict__ x, float* __restrict__ xT) {
    int i = blockIdx.x * 256 + threadIdx.x;
    if (i < 131072) {
        int mt = i >> 2, q = i & 3;
        int m = mt >> 9, t = mt & 511;
        float4 v = *(const float4*)(x + (size_t)i * 4);
        *(float4*)(xT + ((size_t)t * 64 + m) * 16 + q * 4) = v;
    }
}

// Persistent cooperative kernel (512 thr, 8 waves, k-split 64/wave).
// R12: b128 weight reads (halves DS issue), prefetch-all h cloads (latency
// exposed once), combine phases split across waves v0/v1 (one column each),
// uniform steps (initial h pre-copied into parity buffers by k_init).
__global__ __launch_bounds__(NTH, 2)
void k_fused(const float* __restrict__ xT,
             const float* __restrict__ Wih0, const float* __restrict__ Whh0,
             const float* __restrict__ bih0, const float* __restrict__ bhh0,
             const float* __restrict__ Wih1, const float* __restrict__ Whh1,
             const float* __restrict__ bih1, const float* __restrict__ bhh1,
             const float* __restrict__ fcW, const float* __restrict__ fcb,
             const float* __restrict__ th0, const float* __restrict__ om0,
             float* __restrict__ out,
             float* __restrict__ h0buf, float* __restrict__ h1buf,
             float* __restrict__ apre_g, unsigned* __restrict__ bar)
{
    const int w = blockIdx.x, tid = threadIdx.x;
    const int v = tid >> 6, m = tid & 63;
    const int c0 = w * 2;
    const int ks = v * 64;
    unsigned* treeA = bar;          // h0 barrier
    unsigned* treeB = bar + 320;    // h1 barrier
    __shared__ __align__(16) float w0s[6 * 512];   // Whh0 rows (g = gate*2 + j)
    __shared__ __align__(16) float wi1s[6 * 512];  // Wih1 rows
    __shared__ __align__(16) float w1s[6 * 512];   // Whh1 rows
    __shared__ __align__(16) float wihs[6 * 16];   // Wih0 rows
    __shared__ __align__(16) float fcrow[512];     // fc row (WGs 8..23)
    __shared__ float pl[8 * 12 * 64];
    __shared__ float pl2[8 * 64];

    for (int i = tid; i < 6 * 128; i += NTH) {
        int g = i >> 7, q = (i & 127) * 4;
        int row = (g >> 1) * 512 + c0 + (g & 1);
        *(float4*)&w0s[g * 512 + q]  = *(const float4*)(Whh0 + (size_t)row * 512 + q);
        *(float4*)&wi1s[g * 512 + q] = *(const float4*)(Wih1 + (size_t)row * 512 + q);
        *(float4*)&w1s[g * 512 + q]  = *(const float4*)(Whh1 + (size_t)row * 512 + q);
    }
    if (tid < 24) {
        int g = tid >> 2, q = (tid & 3) * 4;
        int row = (g >> 1) * 512 + c0 + (g & 1);
        *(float4*)&wihs[g * 16 + q] = *(const float4*)(Wih0 + (size_t)row * 16 + q);
    }
    const bool isFC = (w >= 8 && w < 24);
    if (isFC && tid < 128)
        *(float4*)&fcrow[tid * 4] = *(const float4*)(fcW + (size_t)(w - 8) * 512 + tid * 4);

    // wave v<2 owns column c0+v in the combine phases
    float br0=0, bz0=0, bin0=0, bhn0=0, bi1r=0, bi1z=0, bi1n=0, bh1r=0, bh1z=0, bh1n=0;
    if (v < 2) {
        int c = c0 + v;
        br0  = bih0[c] + bhh0[c];
        bz0  = bih0[512 + c] + bhh0[512 + c];
        bin0 = bih0[1024 + c]; bhn0 = bhh0[1024 + c];
        bi1r = bih1[c]; bi1z = bih1[512 + c]; bi1n = bih1[1024 + c];
        bh1r = bhh1[c]; bh1z = bhh1[512 + c]; bh1n = bhh1[1024 + c];
    }
    // biophys state: WG 0, thread = chain*8 + joint
    float th = 0.f, om = 0.f, fb0 = 0.f, fb1 = 0.f;
    if (w == 0) {
        th = th0[tid]; om = om0[tid];
        fb0 = fcb[2 * (tid & 7)]; fb1 = fcb[2 * (tid & 7) + 1];
    }
    float gi_r = 0.f, gi_z = 0.f, gi_n = 0.f;
    __syncthreads();

    for (int s = 0; s < 515; ++s) {
        const int pw0 = s & 1, pr0 = (s + 1) & 1;
        // ---- wait-h0(s): h0(s-1) pairs visible (arrived mid-step s-1) ----
        if (s >= 1) {
            if (tid == 0) bar_wait(treeA, (unsigned)s);
            __syncthreads();
        }
        // ---- fused phase 1+2: Whh0 & Wih1 dots over h0(s-1) ----
        if (s <= 512) {
            vf2 hb[32];
            const float* hpb = h0buf + pr0 * 32768 + (ks >> 1) * 128 + m * 2;
            #pragma unroll
            for (int i = 0; i < 32; ++i) hb[i] = cload2(hpb + i * 128);
            vf2 a01[12];
            #pragma unroll
            for (int g = 0; g < 12; ++g) a01[g] = (vf2){0.f, 0.f};
            #pragma unroll
            for (int q = 0; q < 16; ++q) {
                vf2 h0v = hb[2 * q], h1v = hb[2 * q + 1];
                int ko = ks + q * 4;
                #pragma unroll
                for (int g = 0; g < 6; ++g) {
                    float4 w0 = *(const float4*)&w0s[g * 512 + ko];
                    a01[g] += ((vf2){w0.x, w0.y}) * h0v + ((vf2){w0.z, w0.w}) * h1v;
                    float4 wi = *(const float4*)&wi1s[g * 512 + ko];
                    a01[6 + g] += ((vf2){wi.x, wi.y}) * h0v + ((vf2){wi.z, wi.w}) * h1v;
                }
            }
            #pragma unroll
            for (int g = 0; g < 12; ++g) pl[(v * 12 + g) * 64 + m] = a01[g].x + a01[g].y;
        }
        __syncthreads();
        // ---- combine A (waves v0,v1; col c0+v): h0(s) update + gi1 regs ----
        if (v < 2) {
            if (s <= 511) {
                float hold = cload(&h0buf[pr0 * 32768 + w * 128 + m * 2 + v]);
                float hr = 0.f, hz = 0.f, hn = 0.f;
                #pragma unroll
                for (int u = 0; u < 8; ++u) {
                    hr += pl[(u * 12 + 0 + v) * 64 + m];
                    hz += pl[(u * 12 + 2 + v) * 64 + m];
                    hn += pl[(u * 12 + 4 + v) * 64 + m];
                }
                const float* xp = xT + ((size_t)s * 64 + m) * 16;
                float ir = 0.f, iz = 0.f, in_ = 0.f;
                #pragma unroll
                for (int k = 0; k < 16; ++k) {
                    float xv = xp[k];
                    ir  += wihs[(0 + v) * 16 + k] * xv;
                    iz  += wihs[(2 + v) * 16 + k] * xv;
                    in_ += wihs[(4 + v) * 16 + k] * xv;
                }
                float r = 1.f / (1.f + expf(-(ir + hr + br0)));
                float z = 1.f / (1.f + expf(-(iz + hz + bz0)));
                float n = tanhf(in_ + bin0 + r * (hn + bhn0));
                cstore(&h0buf[pw0 * 32768 + w * 128 + m * 2 + v], (1.f - z) * n + z * hold);
            }
            if (s >= 1 && s <= 512) {
                gi_r = bi1r; gi_z = bi1z; gi_n = bi1n;
                #pragma unroll
                for (int u = 0; u < 8; ++u) {
                    gi_r += pl[(u * 12 + 6 + v) * 64 + m];
                    gi_z += pl[(u * 12 + 8 + v) * 64 + m];
                    gi_n += pl[(u * 12 + 10 + v) * 64 + m];
                }
            }
        }
        // ---- arrive-h0(s+1) + wait-h1(s) ----
        __syncthreads();                 // drains h0 cstores for all waves
        if (tid == 0) {
            bar_arrive(treeA, w, (unsigned)(s + 1));
            bar_wait(treeB, (unsigned)s);
        }
        __syncthreads();
        // ---- biophys (WG0): consume apre(s-1) -> theta(s-3) ----
        if (w == 0 && s >= 3) {
            int mc = tid >> 3, j = tid & 7;
            const float* ap = apre_g + ((s + 1) & 1) * 1024;
            float a0 = 1.f / (1.f + expf(-(cload(&ap[(2 * j) * 64 + mc]) + fb0)));
            float a1 = 1.f / (1.f + expf(-(cload(&ap[(2 * j + 1) * 64 + mc]) + fb1)));
            float F0 = (100.f + 2000.f * a0) * (0.06f + 0.006f * a0 + 0.05f * th);
            float F1 = (100.f + 2000.f * a1) * (0.06f + 0.006f * a1 - 0.05f * th);
            float tau = 0.05f * (F1 - F0);
            float acc = (tau - 5.f * th - 0.3f * om) * 250.f;
            om += (1.f / 60.f) * acc;
            th += (1.f / 60.f) * om;
            out[((size_t)mc * 512 + (s - 3)) * 8 + j] = th;
        }
        // ---- phase 3: Whh1 + FC dots over h1 ----
        if (s >= 1 && s <= 513) {
            vf2 hb[32];
            const float* hpb = h1buf + (s & 1) * 32768 + (ks >> 1) * 128 + m * 2;
            #pragma unroll
            for (int i = 0; i < 32; ++i) hb[i] = cload2(hpb + i * 128);
            vf2 a2[6];
            #pragma unroll
            for (int g = 0; g < 6; ++g) a2[g] = (vf2){0.f, 0.f};
            vf2 fd = {0.f, 0.f};
            #pragma unroll
            for (int q = 0; q < 16; ++q) {
                vf2 h0v = hb[2 * q], h1v = hb[2 * q + 1];
                int ko = ks + q * 4;
                #pragma unroll
                for (int g = 0; g < 6; ++g) {
                    float4 w1 = *(const float4*)&w1s[g * 512 + ko];
                    a2[g] += ((vf2){w1.x, w1.y}) * h0v + ((vf2){w1.z, w1.w}) * h1v;
                }
                float4 fc4 = *(const float4*)&fcrow[ko];
                fd += ((vf2){fc4.x, fc4.y}) * h0v + ((vf2){fc4.z, fc4.w}) * h1v;
            }
            if (s <= 512) {
                #pragma unroll
                for (int g = 0; g < 6; ++g) pl[(v * 12 + g) * 64 + m] = a2[g].x + a2[g].y;
            }
            if (isFC && s >= 2) pl2[v * 64 + m] = fd.x + fd.y;
        }
        __syncthreads();
        // ---- combine B (waves v0,v1; col c0+v): h1(s) update ----
        if (s >= 1 && s <= 512 && v < 2) {
            float hold = cload(&h1buf[(s & 1) * 32768 + w * 128 + m * 2 + v]);
            float hr = 0.f, hz = 0.f, hn = 0.f;
            #pragma unroll
            for (int u = 0; u < 8; ++u) {
                hr += pl[(u * 12 + 0 + v) * 64 + m];
                hz += pl[(u * 12 + 2 + v) * 64 + m];
                hn += pl[(u * 12 + 4 + v) * 64 + m];
            }
            float r = 1.f / (1.f + expf(-(gi_r + hr + bh1r)));
            float z = 1.f / (1.f + expf(-(gi_z + hz + bh1z)));
            float n = tanhf(gi_n + r * (hn + bh1n));
            cstore(&h1buf[((s + 1) & 1) * 32768 + w * 128 + m * 2 + v], (1.f - z) * n + z * hold);
        }
        if (isFC && s >= 2 && s <= 513 && v == 2) {
            float p = 0.f;
            #pragma unroll
            for (int u = 0; u < 8; ++u) p += pl2[u * 64 + m];
            cstore(&apre_g[(s & 1) * 1024 + (w - 8) * 64 + m], p);
        }
        if (s == 514) break;
        // ---- arrive-h1(s+1): end of step ----
        __syncthreads();                 // drains h1/apre cstores
        if (tid == 0) bar_arrive(treeB, w, (unsigned)(s + 1));
    }
}

// ---------------------------------------------------------------------------
extern "C" void kernel_launch(void* const* d_in, const int* in_sizes, int n_in,
                              void* d_out, int out_size, void* d_ws, size_t ws_size,
                              hipStream_t stream) {
    const float* x     = (const float*)d_in[0];
    const float* W_ih0 = (const float*)d_in[1];
    const float* W_hh0 = (const float*)d_in[2];
    const float* b_ih0 = (const float*)d_in[3];
    const float* b_hh0 = (const float*)d_in[4];
    const float* W_ih1 = (const float*)d_in[5];
    const float* W_hh1 = (const float*)d_in[6];
    const float* b_ih1 = (const float*)d_in[7];
    const float* b_hh1 = (const float*)d_in[8];
    const float* fc_W  = (const float*)d_in[9];
    const float* fc_b  = (const float*)d_in[10];
    const float* h0    = (const float*)d_in[11];
    const float* th0   = (const float*)d_in[12];
    const float* om0   = (const float*)d_in[13];
    float* out = (float*)d_out;

    float* ws = (float*)d_ws;
    float* h0buf  = ws;                 // 2 x [256 pairs][64 chains][2] parity buffers
    float* h1buf  = h0buf + 65536;
    float* apre_g = h1buf + 65536;      // 2 x [16][64]
    unsigned* bar = (unsigned*)(apre_g + 2048);    // 1024 uints (two trees)
    float* xT     = (float*)(bar + 1024);          // [512][64][16]

    k_init<<<260, 256, 0, stream>>>(h0, h0buf, h1buf, bar);
    k_xt<<<512, 256, 0, stream>>>(x, xT);

    void* args[] = {(void*)&xT, (void*)&W_ih0, (void*)&W_hh0, (void*)&b_ih0,
                    (void*)&b_hh0, (void*)&W_ih1, (void*)&W_hh1, (void*)&b_ih1,
                    (void*)&b_hh1, (void*)&fc_W, (void*)&fc_b,
                    (void*)&th0, (void*)&om0, (void*)&out, (void*)&h0buf,
                    (void*)&h1buf, (void*)&apre_g, (void*)&bar};
    (void)hipLaunchCooperativeKernel((void*)k_fused, dim3(NWG), dim3(NTH),
                                     args, 0, stream);
}

// Round 13
// 5075.751 us; speedup vs baseline: 1.2343x; 1.2343x over previous
//
#include <hip/hip_runtime.h>
#include <math.h>

#define NWG 256
#define NTH 512

typedef float vf2 __attribute__((ext_vector_type(2)));

// agent-coherent (L2-bypassing) access — cross-XCD exchange primitives
__device__ __forceinline__ float cload(const float* p) {
    return __hip_atomic_load(p, __ATOMIC_RELAXED, __HIP_MEMORY_SCOPE_AGENT);
}
__device__ __forceinline__ void cstore(float* p, float v) {
    __hip_atomic_store(p, v, __ATOMIC_RELAXED, __HIP_MEMORY_SCOPE_AGENT);
}
__device__ __forceinline__ vf2 cload2(const float* p) {
    unsigned long long u = __hip_atomic_load((const unsigned long long*)p,
                                             __ATOMIC_RELAXED, __HIP_MEMORY_SCOPE_AGENT);
    vf2 r;
    r.x = __uint_as_float((unsigned)u);
    r.y = __uint_as_float((unsigned)(u >> 32));
    return r;
}
__device__ __forceinline__ void cstore2(float* p, vf2 v) {
    unsigned long long u = ((unsigned long long)__float_as_uint(v.y) << 32)
                         | (unsigned long long)__float_as_uint(v.x);
    __hip_atomic_store((unsigned long long*)p, u,
                       __ATOMIC_RELAXED, __HIP_MEMORY_SCOPE_AGENT);
}

// two-level arrive (16 groups x 16 WGs); gen monotonic, counters never reset
__device__ __forceinline__ void bar_arrive(unsigned* tree, int w, unsigned gen) {
    unsigned p = __hip_atomic_fetch_add(&tree[(w >> 4) * 16], 1u,
                                        __ATOMIC_RELAXED, __HIP_MEMORY_SCOPE_AGENT);
    if (p + 1u == 16u * gen) {
        unsigned q = __hip_atomic_fetch_add(&tree[272], 1u,
                                            __ATOMIC_RELAXED, __HIP_MEMORY_SCOPE_AGENT);
        if (q + 1u == 16u * gen)
            __hip_atomic_store(&tree[288], gen,
                               __ATOMIC_RELAXED, __HIP_MEMORY_SCOPE_AGENT);
    }
}
__device__ __forceinline__ void bar_wait(unsigned* tree, unsigned gen) {
    unsigned f;
    do {
        f = __hip_atomic_load(&tree[288], __ATOMIC_RELAXED, __HIP_MEMORY_SCOPE_AGENT);
        if (f < gen) __builtin_amdgcn_s_sleep(2);
    } while (f < gen);
}

// init: initial h states -> pair-layout parity-1 buffers; zero barriers
__global__ void k_init(const float* __restrict__ h0in, float* __restrict__ h0buf,
                       float* __restrict__ h1buf, unsigned* __restrict__ bar) {
    int i = blockIdx.x * 256 + threadIdx.x;
    if (i < 32768) {
        int m = i >> 9, k = i & 511;
        h0buf[32768 + ((k >> 1) << 7) + (m << 1) + (k & 1)] = h0in[i];
    } else if (i < 65536) {
        int j = i - 32768;
        int m = j >> 9, k = j & 511;
        h1buf[32768 + ((k >> 1) << 7) + (m << 1) + (k & 1)] = h0in[i];
    } else if (i < 66560) {
        bar[i - 65536] = 0u;
    }
}

// transpose x [64][512][16] -> xT [512][64][16]
__global__ void k_xt(const float* __restrict__ x, float* __restrict__ xT) {
    int i = blockIdx.x * 256 + threadIdx.x;
    if (i < 131072) {
        int mt = i >> 2, q = i & 3;
        int m = mt >> 9, t = mt & 511;
        float4 v = *(const float4*)(x + (size_t)i * 4);
        *(float4*)(xT + ((size_t)t * 64 + m) * 16 + q * 4) = v;
    }
}

// Persistent cooperative kernel (512 thr, 8 waves, k-split 64/wave).
// R13: weights read via WAVE-UNIFORM (readfirstlane-forced) global pointers ->
// scalar s_load path, OFF the DS pipe (which was the ~10.5 us/step floor:
// ~4.9K ds_read broadcasts/CU/step in R8-R12). LDS keeps only the pl
// reduction buffers. h-exchange: packed-pair agent-coherent, v0 combine with
// cstore2 (no write amplification). Split barriers as R10/R11.
__global__ __launch_bounds__(NTH, 2)
void k_fused(const float* __restrict__ xT,
             const float* __restrict__ Wih0, const float* __restrict__ Whh0,
             const float* __restrict__ bih0, const float* __restrict__ bhh0,
             const float* __restrict__ Wih1, const float* __restrict__ Whh1,
             const float* __restrict__ bih1, const float* __restrict__ bhh1,
             const float* __restrict__ fcW, const float* __restrict__ fcb,
             const float* __restrict__ th0, const float* __restrict__ om0,
             float* __restrict__ out,
             float* __restrict__ h0buf, float* __restrict__ h1buf,
             float* __restrict__ apre_g, unsigned* __restrict__ bar)
{
    const int w = blockIdx.x, tid = threadIdx.x;
    const int v = tid >> 6, m = tid & 63;
    const int c0 = w * 2;
    // wave-uniform k-slice base: forces scalar (s_load) weight fetches
    const int vu = __builtin_amdgcn_readfirstlane(v);
    const int ksu = vu * 64;
    unsigned* treeA = bar;          // h0 barrier
    unsigned* treeB = bar + 320;    // h1 barrier
    __shared__ float pl[8 * 12 * 64];
    __shared__ float pl2[8 * 64];

    // uniform row base pointers (local gate g = gt*2 + j, j = column)
    const float* wp0[6]; const float* wpi[6]; const float* wp1[6];
    #pragma unroll
    for (int g = 0; g < 6; ++g) {
        int row = (g >> 1) * 512 + c0 + (g & 1);
        wp0[g] = Whh0 + (size_t)row * 512 + ksu;
        wpi[g] = Wih1 + (size_t)row * 512 + ksu;
        wp1[g] = Whh1 + (size_t)row * 512 + ksu;
    }
    const bool isFC = (w >= 8 && w < 24);
    const float* fcp = fcW + (size_t)(isFC ? (w - 8) : 0) * 512 + ksu;

    // v0 holds biases for BOTH columns as float2
    vf2 br0 = {0,0}, bz0 = {0,0}, bin0 = {0,0}, bhn0 = {0,0};
    vf2 bi1r = {0,0}, bi1z = {0,0}, bi1n = {0,0};
    vf2 bh1r = {0,0}, bh1z = {0,0}, bh1n = {0,0};
    if (v == 0) {
        #pragma unroll
        for (int j = 0; j < 2; ++j) {
            int c = c0 + j;
            br0[j]  = bih0[c] + bhh0[c];
            bz0[j]  = bih0[512 + c] + bhh0[512 + c];
            bin0[j] = bih0[1024 + c]; bhn0[j] = bhh0[1024 + c];
            bi1r[j] = bih1[c]; bi1z[j] = bih1[512 + c]; bi1n[j] = bih1[1024 + c];
            bh1r[j] = bhh1[c]; bh1z[j] = bhh1[512 + c]; bh1n[j] = bhh1[1024 + c];
        }
    }
    // biophys state: WG 0, thread = chain*8 + joint
    float th = 0.f, om = 0.f, fb0 = 0.f, fb1 = 0.f;
    if (w == 0) {
        th = th0[tid]; om = om0[tid];
        fb0 = fcb[2 * (tid & 7)]; fb1 = fcb[2 * (tid & 7) + 1];
    }
    vf2 gi_r = {0,0}, gi_z = {0,0}, gi_n = {0,0};
    __syncthreads();

    for (int s = 0; s < 515; ++s) {
        const int pw0 = s & 1, pr0 = (s + 1) & 1;
        // ---- wait-h0(s): h0(s-1) pairs visible (arrived mid-step s-1) ----
        if (s >= 1) {
            if (tid == 0) bar_wait(treeA, (unsigned)s);
            __syncthreads();
        }
        // ---- fused phase 1+2: Whh0 & Wih1 dots over h0(s-1) ----
        if (s <= 512) {
            vf2 a01[12];
            #pragma unroll
            for (int g = 0; g < 12; ++g) a01[g] = (vf2){0.f, 0.f};
            #pragma unroll 1
            for (int kb = 0; kb < 4; ++kb) {
                vf2 hb[8];
                const float* hp = h0buf + pr0 * 32768 + (ksu / 2 + kb * 8) * 128 + m * 2;
                #pragma unroll
                for (int i = 0; i < 8; ++i) hb[i] = cload2(hp + i * 128);
                #pragma unroll
                for (int i = 0; i < 8; ++i) {
                    vf2 hv = hb[i];
                    int ko = kb * 16 + i * 2;
                    #pragma unroll
                    for (int g = 0; g < 6; ++g) {
                        a01[g]     += (*(const vf2*)(wp0[g] + ko)) * hv;
                        a01[6 + g] += (*(const vf2*)(wpi[g] + ko)) * hv;
                    }
                }
            }
            #pragma unroll
            for (int g = 0; g < 12; ++g) pl[(v * 12 + g) * 64 + m] = a01[g].x + a01[g].y;
        }
        __syncthreads();
        // ---- combine A (v0, both columns): h0(s) paired update + gi1 regs ----
        if (v == 0) {
            if (s <= 511) {
                vf2 hr = {0,0}, hz = {0,0}, hn = {0,0};
                #pragma unroll
                for (int u = 0; u < 8; ++u) {
                    hr.x += pl[(u * 12 + 0) * 64 + m]; hr.y += pl[(u * 12 + 1) * 64 + m];
                    hz.x += pl[(u * 12 + 2) * 64 + m]; hz.y += pl[(u * 12 + 3) * 64 + m];
                    hn.x += pl[(u * 12 + 4) * 64 + m]; hn.y += pl[(u * 12 + 5) * 64 + m];
                }
                const float* xp = xT + ((size_t)s * 64 + m) * 16;
                vf2 ir = {0,0}, iz = {0,0}, in_ = {0,0};
                #pragma unroll
                for (int k = 0; k < 16; ++k) {
                    float xv = xp[k];
                    // uniform scalar reads of Wih0 rows (row = gt*512 + c0 + j)
                    ir.x  += Wih0[(size_t)(c0) * 16 + k] * xv;
                    ir.y  += Wih0[(size_t)(c0 + 1) * 16 + k] * xv;
                    iz.x  += Wih0[(size_t)(512 + c0) * 16 + k] * xv;
                    iz.y  += Wih0[(size_t)(512 + c0 + 1) * 16 + k] * xv;
                    in_.x += Wih0[(size_t)(1024 + c0) * 16 + k] * xv;
                    in_.y += Wih0[(size_t)(1024 + c0 + 1) * 16 + k] * xv;
                }
                vf2 hold = cload2(&h0buf[pr0 * 32768 + w * 128 + m * 2]);
                vf2 hnew;
                #pragma unroll
                for (int j = 0; j < 2; ++j) {
                    float r = 1.f / (1.f + expf(-(ir[j] + hr[j] + br0[j])));
                    float z = 1.f / (1.f + expf(-(iz[j] + hz[j] + bz0[j])));
                    float n = tanhf(in_[j] + bin0[j] + r * (hn[j] + bhn0[j]));
                    hnew[j] = (1.f - z) * n + z * hold[j];
                }
                cstore2(&h0buf[pw0 * 32768 + w * 128 + m * 2], hnew);
            }
            if (s >= 1 && s <= 512) {
                gi_r = bi1r; gi_z = bi1z; gi_n = bi1n;
                #pragma unroll
                for (int u = 0; u < 8; ++u) {
                    gi_r.x += pl[(u * 12 + 6) * 64 + m];  gi_r.y += pl[(u * 12 + 7) * 64 + m];
                    gi_z.x += pl[(u * 12 + 8) * 64 + m];  gi_z.y += pl[(u * 12 + 9) * 64 + m];
                    gi_n.x += pl[(u * 12 + 10) * 64 + m]; gi_n.y += pl[(u * 12 + 11) * 64 + m];
                }
            }
        }
        // ---- arrive-h0(s+1) + wait-h1(s) ----
        __syncthreads();                 // drains h0 cstores for all waves
        if (tid == 0) {
            bar_arrive(treeA, w, (unsigned)(s + 1));
            bar_wait(treeB, (unsigned)s);
        }
        __syncthreads();
        // ---- biophys (WG0): consume apre(s-1) -> theta(s-3) ----
        if (w == 0 && s >= 3) {
            int mc = tid >> 3, j = tid & 7;
            const float* ap = apre_g + ((s + 1) & 1) * 1024;
            float a0 = 1.f / (1.f + expf(-(cload(&ap[(2 * j) * 64 + mc]) + fb0)));
            float a1 = 1.f / (1.f + expf(-(cload(&ap[(2 * j + 1) * 64 + mc]) + fb1)));
            float F0 = (100.f + 2000.f * a0) * (0.06f + 0.006f * a0 + 0.05f * th);
            float F1 = (100.f + 2000.f * a1) * (0.06f + 0.006f * a1 - 0.05f * th);
            float tau = 0.05f * (F1 - F0);
            float acc = (tau - 5.f * th - 0.3f * om) * 250.f;
            om += (1.f / 60.f) * acc;
            th += (1.f / 60.f) * om;
            out[((size_t)mc * 512 + (s - 3)) * 8 + j] = th;
        }
        // ---- phase 3: Whh1 + FC dots over h1(s-1), packed pairs ----
        if (s >= 1 && s <= 513) {
            vf2 a2[6];
            #pragma unroll
            for (int g = 0; g < 6; ++g) a2[g] = (vf2){0.f, 0.f};
            vf2 fd = {0.f, 0.f};
            #pragma unroll 1
            for (int kb = 0; kb < 4; ++kb) {
                vf2 hb[8];
                const float* hp = h1buf + (s & 1) * 32768 + (ksu / 2 + kb * 8) * 128 + m * 2;
                #pragma unroll
                for (int i = 0; i < 8; ++i) hb[i] = cload2(hp + i * 128);
                #pragma unroll
                for (int i = 0; i < 8; ++i) {
                    vf2 hv = hb[i];
                    int ko = kb * 16 + i * 2;
                    #pragma unroll
                    for (int g = 0; g < 6; ++g)
                        a2[g] += (*(const vf2*)(wp1[g] + ko)) * hv;
                    fd += (*(const vf2*)(fcp + ko)) * hv;
                }
            }
            if (s <= 512) {
                #pragma unroll
                for (int g = 0; g < 6; ++g) pl[(v * 12 + g) * 64 + m] = a2[g].x + a2[g].y;
            }
            if (isFC && s >= 2) pl2[v * 64 + m] = fd.x + fd.y;
        }
        __syncthreads();
        // ---- combine B (v0, both columns): h1(s) paired update ----
        if (s >= 1 && s <= 512 && v == 0) {
            vf2 hr = {0,0}, hz = {0,0}, hn = {0,0};
            #pragma unroll
            for (int u = 0; u < 8; ++u) {
                hr.x += pl[(u * 12 + 0) * 64 + m]; hr.y += pl[(u * 12 + 1) * 64 + m];
                hz.x += pl[(u * 12 + 2) * 64 + m]; hz.y += pl[(u * 12 + 3) * 64 + m];
                hn.x += pl[(u * 12 + 4) * 64 + m]; hn.y += pl[(u * 12 + 5) * 64 + m];
            }
            vf2 hold = cload2(&h1buf[(s & 1) * 32768 + w * 128 + m * 2]);
            vf2 hnew;
            #pragma unroll
            for (int j = 0; j < 2; ++j) {
                float r = 1.f / (1.f + expf(-(gi_r[j] + hr[j] + bh1r[j])));
                float z = 1.f / (1.f + expf(-(gi_z[j] + hz[j] + bh1z[j])));
                float n = tanhf(gi_n[j] + r * (hn[j] + bh1n[j]));
                hnew[j] = (1.f - z) * n + z * hold[j];
            }
            cstore2(&h1buf[((s + 1) & 1) * 32768 + w * 128 + m * 2], hnew);
        }
        if (isFC && s >= 2 && s <= 513 && v == 2) {
            float p = 0.f;
            #pragma unroll
            for (int u = 0; u < 8; ++u) p += pl2[u * 64 + m];
            cstore(&apre_g[(s & 1) * 1024 + (w - 8) * 64 + m], p);
        }
        if (s == 514) break;
        // ---- arrive-h1(s+1): end of step ----
        __syncthreads();                 // drains h1/apre cstores
        if (tid == 0) bar_arrive(treeB, w, (unsigned)(s + 1));
    }
}

// ---------------------------------------------------------------------------
extern "C" void kernel_launch(void* const* d_in, const int* in_sizes, int n_in,
                              void* d_out, int out_size, void* d_ws, size_t ws_size,
                              hipStream_t stream) {
    const float* x     = (const float*)d_in[0];
    const float* W_ih0 = (const float*)d_in[1];
    const float* W_hh0 = (const float*)d_in[2];
    const float* b_ih0 = (const float*)d_in[3];
    const float* b_hh0 = (const float*)d_in[4];
    const float* W_ih1 = (const float*)d_in[5];
    const float* W_hh1 = (const float*)d_in[6];
    const float* b_ih1 = (const float*)d_in[7];
    const float* b_hh1 = (const float*)d_in[8];
    const float* fc_W  = (const float*)d_in[9];
    const float* fc_b  = (const float*)d_in[10];
    const float* h0    = (const float*)d_in[11];
    const float* th0   = (const float*)d_in[12];
    const float* om0   = (const float*)d_in[13];
    float* out = (float*)d_out;

    float* ws = (float*)d_ws;
    float* h0buf  = ws;                 // 2 x [256 pairs][64 chains][2] parity buffers
    float* h1buf  = h0buf + 65536;
    float* apre_g = h1buf + 65536;      // 2 x [16][64]
    unsigned* bar = (unsigned*)(apre_g + 2048);    // 1024 uints (two trees)
    float* xT     = (float*)(bar + 1024);          // [512][64][16]

    k_init<<<260, 256, 0, stream>>>(h0, h0buf, h1buf, bar);
    k_xt<<<512, 256, 0, stream>>>(x, xT);

    void* args[] = {(void*)&xT, (void*)&W_ih0, (void*)&W_hh0, (void*)&b_ih0,
                    (void*)&b_hh0, (void*)&W_ih1, (void*)&W_hh1, (void*)&b_ih1,
                    (void*)&b_hh1, (void*)&fc_W, (void*)&fc_b,
                    (void*)&th0, (void*)&om0, (void*)&out, (void*)&h0buf,
                    (void*)&h1buf, (void*)&apre_g, (void*)&bar};
    (void)hipLaunchCooperativeKernel((void*)k_fused, dim3(NWG), dim3(NTH),
                                     args, 0, stream);
}